// Round 2
// baseline (51.559 us; speedup 1.0000x reference)
//
#include <hip/hip_runtime.h>
#include <stdint.h>

// ExampleTiedDropout: out[b,c,h,w] = X[b,c,h,w] * mask[b,c]
// mask[b, 0:51] = 1
// mask[b, 51:256] = bernoulli(fold_in(key(42), idx[b]), 0.1) over 205 channels
//
// JAX threefry2x32, jax_threefry_partitionable=True semantics:
//   fold_in(key, d): newkey = threefry2x32(key, (0, uint32(d)))
//   random_bits(key, 32, (N,)): bits[i] = y0 ^ y1, (y0,y1)=threefry2x32(key,(0,i))
//   uniform: u = bitcast((bits>>9)|0x3f800000) - 1.0f ;  mask = (u < 0.1f)

#define BDIM   128
#define CDIM   256
#define HWDIM  1024
#define FIXEDC 51
#define MEMC   205   // 256 - 51

__device__ __forceinline__ uint32_t rotl32(uint32_t x, int d) {
    return (x << d) | (x >> (32 - d));
}

// One Threefry-2x32 block cipher (20 rounds), JAX-compatible.
__device__ __forceinline__ void threefry2x32_block(uint32_t k0, uint32_t k1,
                                                   uint32_t c0, uint32_t c1,
                                                   uint32_t& o0, uint32_t& o1) {
    const uint32_t ks0 = k0, ks1 = k1, ks2 = k0 ^ k1 ^ 0x1BD11BDAu;
    uint32_t x0 = c0 + ks0;
    uint32_t x1 = c1 + ks1;
#define TF_R4(r0, r1, r2, r3)                              \
    x0 += x1; x1 = rotl32(x1, r0); x1 ^= x0;               \
    x0 += x1; x1 = rotl32(x1, r1); x1 ^= x0;               \
    x0 += x1; x1 = rotl32(x1, r2); x1 ^= x0;               \
    x0 += x1; x1 = rotl32(x1, r3); x1 ^= x0;
    TF_R4(13, 15, 26, 6);  x0 += ks1; x1 += ks2 + 1u;
    TF_R4(17, 29, 16, 24); x0 += ks2; x1 += ks0 + 2u;
    TF_R4(13, 15, 26, 6);  x0 += ks0; x1 += ks1 + 3u;
    TF_R4(17, 29, 16, 24); x0 += ks1; x1 += ks2 + 4u;
    TF_R4(13, 15, 26, 6);  x0 += ks2; x1 += ks0 + 5u;
#undef TF_R4
    o0 = x0;
    o1 = x1;
}

// bits -> uniform [0,1) -> (u < 0.1) ? 1.0 : 0.0
__device__ __forceinline__ float bits_to_mask(uint32_t bits) {
    uint32_t fb = (bits >> 9) | 0x3f800000u;
    float u = __uint_as_float(fb) - 1.0f;
    return (u < 0.1f) ? 1.0f : 0.0f;
}

// Phase 1: build [B, C] float mask in workspace. One block per example.
__global__ void tied_dropout_mask_kernel(const int* __restrict__ indices,
                                         float* __restrict__ mask) {
    const int b = blockIdx.x;
    const int t = threadIdx.x;

    // fold_in(key(42), idx): cipher with key=(0,42), ctr=(0, idx)
    const uint32_t id = (uint32_t)indices[b];
    uint32_t fk0, fk1;
    threefry2x32_block(0u, 42u, 0u, id, fk0, fk1);

    float* mrow = mask + b * CDIM;
    if (t < FIXEDC) mrow[t] = 1.0f;

    if (t < MEMC) {
        // partitionable random_bits: bits[t] = y0 ^ y1, ctr = (0, t)
        uint32_t y0, y1;
        threefry2x32_block(fk0, fk1, 0u, (uint32_t)t, y0, y1);
        mrow[FIXEDC + t] = bits_to_mask(y0 ^ y1);
    }
}

// Phase 2: out = X * mask[b,c], float4 streaming. H*W = 1024 floats per (b,c).
__global__ void tied_dropout_mul_kernel(const float4* __restrict__ X,
                                        const float* __restrict__ mask,
                                        float4* __restrict__ out,
                                        int total4) {
    const int stride = gridDim.x * blockDim.x;
    for (int i = blockIdx.x * blockDim.x + threadIdx.x; i < total4; i += stride) {
        const int bc = i >> 8;  // (i*4) / 1024 -> b*C + c
        const float m = mask[bc];
        float4 v = X[i];
        v.x *= m; v.y *= m; v.z *= m; v.w *= m;
        out[i] = v;
    }
}

extern "C" void kernel_launch(void* const* d_in, const int* in_sizes, int n_in,
                              void* d_out, int out_size, void* d_ws, size_t ws_size,
                              hipStream_t stream) {
    const float* X = (const float*)d_in[0];
    const int* indices = (const int*)d_in[1];
    float* out = (float*)d_out;
    float* mask = (float*)d_ws;  // B*C floats = 128 KiB

    tied_dropout_mask_kernel<<<BDIM, 256, 0, stream>>>(indices, mask);

    const int total4 = BDIM * CDIM * HWDIM / 4;  // 8388608
    tied_dropout_mul_kernel<<<2048, 256, 0, stream>>>(
        (const float4*)X, mask, (float4*)out, total4);
}

// Round 4
// 44.523 us; speedup vs baseline: 1.1580x; 1.1580x over previous
//
#include <hip/hip_runtime.h>
#include <stdint.h>

// ExampleTiedDropout fused: out[b,c,h,w] = X[b,c,h,w] * mask[b,c]
// mask[b, 0:51] = 1
// mask[b, 51:256] = bernoulli(fold_in(key(42), idx[b]), 0.1) over 205 channels
//
// JAX threefry2x32, jax_threefry_partitionable=True semantics (verified r2):
//   fold_in(key, d): newkey = threefry2x32(key, (0, uint32(d)))
//   random_bits(key, 32, (N,)): bits[i] = y0 ^ y1, (y0,y1)=threefry2x32(key,(0,i))
//   uniform: u = bitcast((bits>>9)|0x3f800000) - 1.0f ;  mask = (u < 0.1f)
//
// Single fused kernel: block = (b, group of 4 channels). Mask ciphers are
// block-uniform (~250 VALU ops) amortized over 16 KB moved per block.
// Nontemporal stores keep X resident in Infinity Cache across replays.

#define BDIM   128
#define CDIM   256
#define FIXEDC 51
#define CPB    4            // channels per block
#define GROUPS (CDIM / CPB) // 64
#define F4_PER_PLANE 256    // 1024 floats = 256 float4 per (b,c) plane

typedef float floatx4 __attribute__((ext_vector_type(4)));  // native clang vector

__device__ __forceinline__ uint32_t rotl32(uint32_t x, int d) {
    return (x << d) | (x >> (32 - d));
}

// One Threefry-2x32 block cipher (20 rounds), JAX-compatible.
__device__ __forceinline__ void threefry2x32_block(uint32_t k0, uint32_t k1,
                                                   uint32_t c0, uint32_t c1,
                                                   uint32_t& o0, uint32_t& o1) {
    const uint32_t ks0 = k0, ks1 = k1, ks2 = k0 ^ k1 ^ 0x1BD11BDAu;
    uint32_t x0 = c0 + ks0;
    uint32_t x1 = c1 + ks1;
#define TF_R4(r0, r1, r2, r3)                              \
    x0 += x1; x1 = rotl32(x1, r0); x1 ^= x0;               \
    x0 += x1; x1 = rotl32(x1, r1); x1 ^= x0;               \
    x0 += x1; x1 = rotl32(x1, r2); x1 ^= x0;               \
    x0 += x1; x1 = rotl32(x1, r3); x1 ^= x0;
    TF_R4(13, 15, 26, 6);  x0 += ks1; x1 += ks2 + 1u;
    TF_R4(17, 29, 16, 24); x0 += ks2; x1 += ks0 + 2u;
    TF_R4(13, 15, 26, 6);  x0 += ks0; x1 += ks1 + 3u;
    TF_R4(17, 29, 16, 24); x0 += ks1; x1 += ks2 + 4u;
    TF_R4(13, 15, 26, 6);  x0 += ks2; x1 += ks0 + 5u;
#undef TF_R4
    o0 = x0;
    o1 = x1;
}

__device__ __forceinline__ float bits_to_mask(uint32_t bits) {
    uint32_t fb = (bits >> 9) | 0x3f800000u;
    float u = __uint_as_float(fb) - 1.0f;
    return (u < 0.1f) ? 1.0f : 0.0f;
}

__global__ __launch_bounds__(256) void tied_dropout_fused_kernel(
        const floatx4* __restrict__ X,
        const int* __restrict__ indices,
        floatx4* __restrict__ out) {
    const int g = blockIdx.x;        // [0, B*GROUPS)
    const int b = g >> 6;            // g / GROUPS
    const int c0 = (g & 63) * CPB;   // first channel of this block's group
    const int t = threadIdx.x;

    // fold_in(key(42), idx[b]) — block-uniform
    const uint32_t id = (uint32_t)indices[b];
    uint32_t fk0, fk1;
    threefry2x32_block(0u, 42u, 0u, id, fk0, fk1);

    // per-channel masks for this group (block-uniform)
    float m[CPB];
#pragma unroll
    for (int j = 0; j < CPB; ++j) {
        const int c = c0 + j;
        if (c < FIXEDC) {
            m[j] = 1.0f;
        } else {
            uint32_t y0, y1;
            threefry2x32_block(fk0, fk1, 0u, (uint32_t)(c - FIXEDC), y0, y1);
            m[j] = bits_to_mask(y0 ^ y1);
        }
    }

    const int base = g * (CPB * F4_PER_PLANE) + t;  // float4 index
#pragma unroll
    for (int j = 0; j < CPB; ++j) {
        const int i = base + j * F4_PER_PLANE;
        floatx4 v = X[i];
        v *= m[j];
        __builtin_nontemporal_store(v, &out[i]);
    }
}

extern "C" void kernel_launch(void* const* d_in, const int* in_sizes, int n_in,
                              void* d_out, int out_size, void* d_ws, size_t ws_size,
                              hipStream_t stream) {
    const floatx4* X = (const floatx4*)d_in[0];
    const int* indices = (const int*)d_in[1];
    floatx4* out = (floatx4*)d_out;

    const int nblocks = BDIM * GROUPS;  // 8192
    tied_dropout_fused_kernel<<<nblocks, 256, 0, stream>>>(X, indices, out);
}